// Round 3
// baseline (2171.378 us; speedup 1.0000x reference)
//
#include <hip/hip_runtime.h>
#include <hip/hip_bf16.h>

// LightGCN 3-hop GraphConv (M4_86749749444857).
// Inputs: user_embed [100000,64], item_embed [50000,64] (bf16 OR fp32 —
// detected at runtime), row/col int32 [NNZ], vals [NNZ] (bf16 OR fp32).
// Output FP32: out[0:N*64) = mean(h1,h2,h3); out[N*64:2N*64) = h1.
//
// Pipeline: dtype-detect -> counting-sort COO->CSR (hist, 1-block scan,
// scatter w/ fp32 val conversion, (col,val) interleaved int2) -> 3 atomic-free
// SpMM passes, one wave per row, lane = dim. fp32 accumulation; hop3 fuses
// the mean/layer epilogue.

#define D 64
typedef unsigned short u16;

__device__ __forceinline__ float bf2f(u16 h) {
    union { unsigned int u; float f; } c;
    c.u = ((unsigned int)h) << 16;
    return c.f;
}

// ---------------- dtype sniffing ----------------
// Even-indexed u16s: for bf16 data these are real bf16 values (sane
// exponents); for fp32 data they are low mantissa halves (random exponents).
// 1024 samples each; flags[k] = count of "sane" samples, consumers test >=512.
__global__ void detect_kernel(const u16* __restrict__ emb,
                              const u16* __restrict__ vals,
                              int* __restrict__ flags) {
    int lane = threadIdx.x;  // 64 threads, 1 block
    int se = 0, sv = 0;
    for (int k = 0; k < 16; ++k) {
        int idx = (lane * 16 + k) * 2;
        u16 he = emb[idx];
        int ee = (he >> 7) & 0xFF;
        if (ee >= 100 && ee < 127) se++;          // |x| in [2^-27, 1)
        u16 hv = vals[idx];
        int ev = (hv >> 7) & 0xFF;
        if ((hv >> 15) == 0 && ev >= 60 && ev < 123) sv++;  // x in (0, 1/16)
    }
    atomicAdd(&flags[0], se);
    atomicAdd(&flags[1], sv);
}

// ---------------- CSR build ----------------

__global__ void hist_kernel(const int* __restrict__ row, int* __restrict__ cnt, int nnz) {
    int i = blockIdx.x * blockDim.x + threadIdx.x;
    if (i < nnz) atomicAdd(&cnt[row[i]], 1);
}

// Single-block exclusive scan: cnt_cursor[i] -> exclusive prefix (in-place),
// rp[0..n] = row pointers.
__global__ void scan_kernel(int* __restrict__ cnt_cursor, int* __restrict__ rp, int n) {
    __shared__ int buf[1024];
    __shared__ int carry_s;
    int tid = threadIdx.x;
    if (tid == 0) carry_s = 0;
    __syncthreads();
    for (int base = 0; base < n; base += 1024) {
        int i = base + tid;
        int v = (i < n) ? cnt_cursor[i] : 0;
        buf[tid] = v;
        __syncthreads();
        for (int off = 1; off < 1024; off <<= 1) {
            int y = (tid >= off) ? buf[tid - off] : 0;
            __syncthreads();
            buf[tid] += y;
            __syncthreads();
        }
        int incl  = buf[tid];
        int total = buf[1023];
        int oldc  = carry_s;
        int excl  = oldc + incl - v;
        if (i < n) { rp[i] = excl; cnt_cursor[i] = excl; }
        __syncthreads();
        if (tid == 0) carry_s = oldc + total;
        __syncthreads();
    }
    if (threadIdx.x == 0) rp[n] = carry_s;
}

__global__ void scatter_kernel(const int* __restrict__ row, const int* __restrict__ col,
                               const void* __restrict__ vals, const int* __restrict__ flags,
                               int* __restrict__ cursor, int2* __restrict__ es, int nnz) {
    int i = blockIdx.x * blockDim.x + threadIdx.x;
    if (i >= nnz) return;
    float v = (flags[1] >= 512) ? bf2f(((const u16*)vals)[i])
                                : ((const float*)vals)[i];
    int r = row[i];
    int p = atomicAdd(&cursor[r], 1);
    es[p] = make_int2(col[i], __float_as_int(v));
}

// ---------------- SpMM passes (one wave per row, lane = dim) ----------------

__global__ __launch_bounds__(256)
void spmm_first_kernel(const void* __restrict__ ue, const void* __restrict__ ie,
                       const int* __restrict__ flags, float* __restrict__ y,
                       const int* __restrict__ rp, const int2* __restrict__ es,
                       int n, int nu) {
    int wid  = (blockIdx.x * blockDim.x + threadIdx.x) >> 6;
    int lane = threadIdx.x & 63;
    if (wid >= n) return;
    int e0 = rp[wid], e1 = rp[wid + 1];
    float acc = 0.f;
    if (flags[0] >= 512) {  // bf16 embeddings
        const u16* u  = (const u16*)ue;
        const u16* it = (const u16*)ie;
        for (int e = e0; e < e1; ++e) {
            int2 p = es[e];
            int c = p.x;
            float v = __int_as_float(p.y);
            const u16* src = (c < nu) ? u + (size_t)c * D : it + (size_t)(c - nu) * D;
            acc += v * bf2f(src[lane]);
        }
    } else {                // fp32 embeddings
        const float* u  = (const float*)ue;
        const float* it = (const float*)ie;
        for (int e = e0; e < e1; ++e) {
            int2 p = es[e];
            int c = p.x;
            float v = __int_as_float(p.y);
            const float* src = (c < nu) ? u + (size_t)c * D : it + (size_t)(c - nu) * D;
            acc += v * src[lane];
        }
    }
    y[(size_t)wid * D + lane] = acc;
}

__global__ __launch_bounds__(256)
void spmm_mid_kernel(const float* __restrict__ x, float* __restrict__ y,
                     const int* __restrict__ rp, const int2* __restrict__ es, int n) {
    int wid  = (blockIdx.x * blockDim.x + threadIdx.x) >> 6;
    int lane = threadIdx.x & 63;
    if (wid >= n) return;
    int e0 = rp[wid], e1 = rp[wid + 1];
    float acc = 0.f;
    for (int e = e0; e < e1; ++e) {
        int2 p = es[e];
        acc += __int_as_float(p.y) * x[(size_t)p.x * D + lane];
    }
    y[(size_t)wid * D + lane] = acc;
}

// hop3 + fused epilogue: out[0:N*D) = (h1+h2+h3)/3 ; out[N*D:2*N*D) = h1
__global__ __launch_bounds__(256)
void spmm_last_kernel(const float* __restrict__ x2, const float* __restrict__ x1,
                      float* __restrict__ out,
                      const int* __restrict__ rp, const int2* __restrict__ es, int n) {
    int wid  = (blockIdx.x * blockDim.x + threadIdx.x) >> 6;
    int lane = threadIdx.x & 63;
    if (wid >= n) return;
    int e0 = rp[wid], e1 = rp[wid + 1];
    float acc = 0.f;
    for (int e = e0; e < e1; ++e) {
        int2 p = es[e];
        acc += __int_as_float(p.y) * x2[(size_t)p.x * D + lane];
    }
    size_t idx = (size_t)wid * D + lane;
    float h1 = x1[idx];
    float h2 = x2[idx];
    out[idx] = (h1 + h2 + acc) * (1.0f / 3.0f);
    out[(size_t)n * D + idx] = h1;
}

// ---------------- launch ----------------

extern "C" void kernel_launch(void* const* d_in, const int* in_sizes, int n_in,
                              void* d_out, int out_size, void* d_ws, size_t ws_size,
                              hipStream_t stream) {
    const void* ue   = d_in[0];
    const void* ie   = d_in[1];
    const int*  row  = (const int*)d_in[2];
    const int*  col  = (const int*)d_in[3];
    const void* vals = d_in[4];

    const int nu  = in_sizes[0] / D;   // 100000
    const int ni  = in_sizes[1] / D;   //  50000
    const int n   = nu + ni;           // 150000
    const int nnz = in_sizes[2];       // 4800000

    // workspace layout (~116.5 MB)
    char* ws = (char*)d_ws;
    float* X1     = (float*)ws;  ws += (size_t)n * D * sizeof(float);
    float* X2     = (float*)ws;  ws += (size_t)n * D * sizeof(float);
    int2*  es     = (int2*)ws;   ws += (size_t)nnz * sizeof(int2);
    int*   rp     = (int*)ws;    ws += (size_t)(n + 1) * sizeof(int);
    int*   cursor = (int*)ws;    ws += (size_t)n * sizeof(int);
    int*   flags  = (int*)ws;    ws += 2 * sizeof(int);

    const int tb = 256;
    const int eblocks = (nnz + tb - 1) / tb;
    const int rblocks = (n + 3) / 4;          // 4 waves (rows) per 256-thr block

    // zero cursor + flags in one shot (they are contiguous)
    hipMemsetAsync(cursor, 0, ((size_t)n + 2) * sizeof(int), stream);
    detect_kernel <<<1, 64, 0, stream>>>((const u16*)ue, (const u16*)vals, flags);
    hist_kernel   <<<eblocks, tb, 0, stream>>>(row, cursor, nnz);
    scan_kernel   <<<1, 1024, 0, stream>>>(cursor, rp, n);
    scatter_kernel<<<eblocks, tb, 0, stream>>>(row, col, vals, flags, cursor, es, nnz);

    spmm_first_kernel<<<rblocks, tb, 0, stream>>>(ue, ie, flags, X1, rp, es, n, nu);
    spmm_mid_kernel  <<<rblocks, tb, 0, stream>>>(X1, X2, rp, es, n);
    spmm_last_kernel <<<rblocks, tb, 0, stream>>>(X2, X1, (float*)d_out,
                                                  rp, es, n);
}

// Round 4
// 1163.343 us; speedup vs baseline: 1.8665x; 1.8665x over previous
//
#include <hip/hip_runtime.h>
#include <hip/hip_bf16.h>

// LightGCN 3-hop GraphConv (M4_86749749444857).
// Inputs: user_embed [100000,64], item_embed [50000,64] (bf16 OR fp32 —
// detected at runtime), row/col int32 [NNZ], vals [NNZ] (bf16 OR fp32).
// Output FP32: out[0:N*64) = mean(h1,h2,h3); out[N*64:2N*64) = h1.
//
// R3->R4: (a) hop inputs stored bf16 (X0=bf16(ego) via convert pass) so every
// gather row is 128B (2 lines) not 256B; (b) edge loop unrolled x4 with 4
// independent accumulators -> 4 outstanding gathers/wave (was latency-bound at
// 1); (c) serial 1-block scan replaced by 3-kernel hierarchical scan.

#define D 64
typedef unsigned short u16;

__device__ __forceinline__ float bf2f(u16 h) {
    union { unsigned int u; float f; } c;
    c.u = ((unsigned int)h) << 16;
    return c.f;
}
__device__ __forceinline__ u16 f2bf(float f) {
    union { float f; unsigned int u; } c; c.f = f;
    unsigned int r = c.u + 0x7FFFu + ((c.u >> 16) & 1u);  // RNE
    return (u16)(r >> 16);
}

struct U4 { u16 a, b, c, d; } __attribute__((aligned(8)));

// ---------------- dtype sniffing ----------------
// Even-indexed u16s: bf16 data -> real bf16 values (sane exponents); fp32
// data -> low mantissa halves (random exponents). flags[k] >= 512 => bf16.
__global__ void detect_kernel(const u16* __restrict__ emb,
                              const u16* __restrict__ vals,
                              int* __restrict__ flags) {
    int lane = threadIdx.x;  // 64 threads, 1 block
    int se = 0, sv = 0;
    for (int k = 0; k < 16; ++k) {
        int idx = (lane * 16 + k) * 2;
        u16 he = emb[idx];
        int ee = (he >> 7) & 0xFF;
        if (ee >= 100 && ee < 127) se++;
        u16 hv = vals[idx];
        int ev = (hv >> 7) & 0xFF;
        if ((hv >> 15) == 0 && ev >= 60 && ev < 123) sv++;
    }
    atomicAdd(&flags[0], se);
    atomicAdd(&flags[1], sv);
}

// ---------------- ego -> bf16 X0 ----------------
__global__ __launch_bounds__(256)
void convert_kernel(const void* __restrict__ ue, const void* __restrict__ ie,
                    const int* __restrict__ flags, u16* __restrict__ x0,
                    int total, int usz) {  // total = n*D, usz = nu*D (both %4==0)
    int i = (blockIdx.x * blockDim.x + threadIdx.x) * 4;
    if (i >= total) return;
    const void* src = (i < usz) ? ue : ie;
    int off = (i < usz) ? i : i - usz;
    U4 o;
    if (flags[0] >= 512) {
        o = *(const U4*)((const u16*)src + off);
    } else {
        const float4 v = *(const float4*)((const float*)src + off);
        o.a = f2bf(v.x); o.b = f2bf(v.y); o.c = f2bf(v.z); o.d = f2bf(v.w);
    }
    *(U4*)(x0 + i) = o;
}

// ---------------- CSR build ----------------
__global__ void hist_kernel(const int* __restrict__ row, int* __restrict__ cnt, int nnz) {
    int i = blockIdx.x * blockDim.x + threadIdx.x;
    if (i < nnz) atomicAdd(&cnt[row[i]], 1);
}

#define CHUNK 1024  // elements per scan block (256 thr x 4)

__global__ __launch_bounds__(256)
void scan_partial_kernel(const int* __restrict__ cnt, int* __restrict__ part, int n) {
    __shared__ int sums[256];
    int b = blockIdx.x, t = threadIdx.x;
    int base = b * CHUNK + t * 4;
    int s = 0;
    for (int k = 0; k < 4; ++k) { int i = base + k; if (i < n) s += cnt[i]; }
    sums[t] = s;
    __syncthreads();
    for (int off = 1; off < 256; off <<= 1) {
        int y = (t >= off) ? sums[t - off] : 0;
        __syncthreads();
        sums[t] += y;
        __syncthreads();
    }
    if (t == 255) part[b] = sums[255];
}

// single block: exclusive-scan the <=1024 block partials; writes rp[n]=total
__global__ void scan_part_kernel(int* __restrict__ part, int* __restrict__ rp,
                                 int nparts, int n) {
    __shared__ int buf[1024];
    int t = threadIdx.x;
    int v = (t < nparts) ? part[t] : 0;
    buf[t] = v;
    __syncthreads();
    for (int off = 1; off < 1024; off <<= 1) {
        int y = (t >= off) ? buf[t - off] : 0;
        __syncthreads();
        buf[t] += y;
        __syncthreads();
    }
    if (t < nparts) part[t] = buf[t] - v;   // exclusive
    if (t == 1023) rp[n] = buf[1023];
}

__global__ __launch_bounds__(256)
void scan_final_kernel(const int* __restrict__ cnt, const int* __restrict__ part,
                       int* __restrict__ rp, int* __restrict__ cursor, int n) {
    __shared__ int sums[256];
    int b = blockIdx.x, t = threadIdx.x;
    int base = b * CHUNK + t * 4;
    int v[4]; int s = 0;
    for (int k = 0; k < 4; ++k) { int i = base + k; v[k] = (i < n) ? cnt[i] : 0; s += v[k]; }
    sums[t] = s;
    __syncthreads();
    for (int off = 1; off < 256; off <<= 1) {
        int y = (t >= off) ? sums[t - off] : 0;
        __syncthreads();
        sums[t] += y;
        __syncthreads();
    }
    int running = part[b] + sums[t] - s;     // block offset + exclusive-within-block
    for (int k = 0; k < 4; ++k) {
        int i = base + k;
        if (i < n) { rp[i] = running; cursor[i] = running; }
        running += v[k];
    }
}

__global__ void scatter_kernel(const int* __restrict__ row, const int* __restrict__ col,
                               const void* __restrict__ vals, const int* __restrict__ flags,
                               int* __restrict__ cursor, int2* __restrict__ es, int nnz) {
    int i = blockIdx.x * blockDim.x + threadIdx.x;
    if (i >= nnz) return;
    float v = (flags[1] >= 512) ? bf2f(((const u16*)vals)[i])
                                : ((const float*)vals)[i];
    int r = row[i];
    int p = atomicAdd(&cursor[r], 1);
    es[p] = make_int2(col[i], __float_as_int(v));
}

// ---------------- SpMM (one wave/row, lane = dim, x4 edge unroll) ----------------

__global__ __launch_bounds__(256)
void spmm_kernel(const u16* __restrict__ x, u16* __restrict__ y,
                 const int* __restrict__ rp, const int2* __restrict__ es, int n) {
    int wid  = (blockIdx.x * blockDim.x + threadIdx.x) >> 6;
    int lane = threadIdx.x & 63;
    if (wid >= n) return;
    int e0 = rp[wid], e1 = rp[wid + 1];
    float a0 = 0.f, a1 = 0.f, a2 = 0.f, a3 = 0.f;
    int e = e0;
    for (; e + 4 <= e1; e += 4) {
        int2 p0 = es[e], p1 = es[e + 1], p2 = es[e + 2], p3 = es[e + 3];
        a0 += __int_as_float(p0.y) * bf2f(x[(p0.x << 6) + lane]);
        a1 += __int_as_float(p1.y) * bf2f(x[(p1.x << 6) + lane]);
        a2 += __int_as_float(p2.y) * bf2f(x[(p2.x << 6) + lane]);
        a3 += __int_as_float(p3.y) * bf2f(x[(p3.x << 6) + lane]);
    }
    for (; e < e1; ++e) {
        int2 p = es[e];
        a0 += __int_as_float(p.y) * bf2f(x[(p.x << 6) + lane]);
    }
    y[(wid << 6) + lane] = f2bf((a0 + a1) + (a2 + a3));
}

// hop3 + fused epilogue: out[0:N*D) = (h1+h2+h3)/3 ; out[N*D:2*N*D) = h1
__global__ __launch_bounds__(256)
void spmm_last_kernel(const u16* __restrict__ x2, const u16* __restrict__ x1,
                      float* __restrict__ out,
                      const int* __restrict__ rp, const int2* __restrict__ es, int n) {
    int wid  = (blockIdx.x * blockDim.x + threadIdx.x) >> 6;
    int lane = threadIdx.x & 63;
    if (wid >= n) return;
    int e0 = rp[wid], e1 = rp[wid + 1];
    float a0 = 0.f, a1 = 0.f, a2 = 0.f, a3 = 0.f;
    int e = e0;
    for (; e + 4 <= e1; e += 4) {
        int2 p0 = es[e], p1 = es[e + 1], p2 = es[e + 2], p3 = es[e + 3];
        a0 += __int_as_float(p0.y) * bf2f(x2[(p0.x << 6) + lane]);
        a1 += __int_as_float(p1.y) * bf2f(x2[(p1.x << 6) + lane]);
        a2 += __int_as_float(p2.y) * bf2f(x2[(p2.x << 6) + lane]);
        a3 += __int_as_float(p3.y) * bf2f(x2[(p3.x << 6) + lane]);
    }
    for (; e < e1; ++e) {
        int2 p = es[e];
        a0 += __int_as_float(p.y) * bf2f(x2[(p.x << 6) + lane]);
    }
    float acc = (a0 + a1) + (a2 + a3);
    int idx = (wid << 6) + lane;
    float h1 = bf2f(x1[idx]);
    float h2 = bf2f(x2[idx]);
    out[idx] = (h1 + h2 + acc) * (1.0f / 3.0f);
    out[(size_t)n * D + idx] = h1;
}

// ---------------- launch ----------------

extern "C" void kernel_launch(void* const* d_in, const int* in_sizes, int n_in,
                              void* d_out, int out_size, void* d_ws, size_t ws_size,
                              hipStream_t stream) {
    const void* ue   = d_in[0];
    const void* ie   = d_in[1];
    const int*  row  = (const int*)d_in[2];
    const int*  col  = (const int*)d_in[3];
    const void* vals = d_in[4];

    const int nu  = in_sizes[0] / D;   // 100000
    const int ni  = in_sizes[1] / D;   //  50000
    const int n   = nu + ni;           // 150000
    const int nnz = in_sizes[2];       // 4800000

    // workspace layout (~98.5 MB)
    char* ws = (char*)d_ws;
    u16*  X0     = (u16*)ws;   ws += (size_t)n * D * sizeof(u16);
    u16*  X1     = (u16*)ws;   ws += (size_t)n * D * sizeof(u16);
    u16*  X2     = (u16*)ws;   ws += (size_t)n * D * sizeof(u16);
    int2* es     = (int2*)ws;  ws += (size_t)nnz * sizeof(int2);
    int*  rp     = (int*)ws;   ws += (size_t)(n + 1) * sizeof(int);
    int*  cnt    = (int*)ws;   ws += (size_t)n * sizeof(int);
    int*  cursor = (int*)ws;   ws += (size_t)n * sizeof(int);
    int*  part   = (int*)ws;   ws += 1024 * sizeof(int);
    int*  flags  = (int*)ws;   ws += 2 * sizeof(int);

    const int tb = 256;
    const int eblocks = (nnz + tb - 1) / tb;
    const int rblocks = (n + 3) / 4;               // 4 waves (rows) / block
    const int cblocks = (n * D / 4 + tb - 1) / tb; // convert
    const int sblocks = (n + CHUNK - 1) / CHUNK;   // 147 scan chunks

    // zero cnt + cursor + part + flags (contiguous tail of workspace)
    hipMemsetAsync(cnt, 0, ((size_t)2 * n + 1024 + 2) * sizeof(int), stream);
    detect_kernel      <<<1, 64, 0, stream>>>((const u16*)ue, (const u16*)vals, flags);
    convert_kernel     <<<cblocks, tb, 0, stream>>>(ue, ie, flags, X0, n * D, nu * D);
    hist_kernel        <<<eblocks, tb, 0, stream>>>(row, cnt, nnz);
    scan_partial_kernel<<<sblocks, tb, 0, stream>>>(cnt, part, n);
    scan_part_kernel   <<<1, 1024, 0, stream>>>(part, rp, sblocks, n);
    scan_final_kernel  <<<sblocks, tb, 0, stream>>>(cnt, part, rp, cursor, n);
    scatter_kernel     <<<eblocks, tb, 0, stream>>>(row, col, vals, flags, cursor, es, nnz);

    spmm_kernel     <<<rblocks, tb, 0, stream>>>(X0, X1, rp, es, n);
    spmm_kernel     <<<rblocks, tb, 0, stream>>>(X1, X2, rp, es, n);
    spmm_last_kernel<<<rblocks, tb, 0, stream>>>(X2, X1, (float*)d_out, rp, es, n);
}

// Round 5
// 951.980 us; speedup vs baseline: 2.2809x; 1.2220x over previous
//
#include <hip/hip_runtime.h>
#include <hip/hip_bf16.h>

// LightGCN 3-hop GraphConv (M4_86749749444857).
// R4->R5: scatter (400us, 7.7x write-amp) replaced by 2-pass sort:
//   coarse: LDS tile-sort (2048 edges) into 293 buckets of 512 rows, run-writes
//   fine:   per bucket-quarter (128 rows) counting-sort in LDS, coalesced out
// Also spmm edge loop unrolled x8 (was x4). es2 aliases X1/X2 (dead by spmm).

#define D 64
typedef unsigned short u16;

#define NBP   512    // padded coarse bucket count (real NB = ceil(n/512))
#define TILE  2048   // edges per coarse block
#define FCAP  4608   // fine LDS slots (lambda=4096 + 8 sigma)

__device__ __forceinline__ float bf2f(u16 h) {
    union { unsigned int u; float f; } c;
    c.u = ((unsigned int)h) << 16;
    return c.f;
}
__device__ __forceinline__ u16 f2bf(float f) {
    union { float f; unsigned int u; } c; c.f = f;
    unsigned int r = c.u + 0x7FFFu + ((c.u >> 16) & 1u);  // RNE
    return (u16)(r >> 16);
}

struct U4 { u16 a, b, c, d; } __attribute__((aligned(8)));

// ---------------- dtype sniffing ----------------
__global__ void detect_kernel(const u16* __restrict__ emb,
                              const u16* __restrict__ vals,
                              int* __restrict__ flags) {
    int lane = threadIdx.x;  // 64 threads, 1 block
    int se = 0, sv = 0;
    for (int k = 0; k < 16; ++k) {
        int idx = (lane * 16 + k) * 2;
        u16 he = emb[idx];
        int ee = (he >> 7) & 0xFF;
        if (ee >= 100 && ee < 127) se++;
        u16 hv = vals[idx];
        int ev = (hv >> 7) & 0xFF;
        if ((hv >> 15) == 0 && ev >= 60 && ev < 123) sv++;
    }
    atomicAdd(&flags[0], se);
    atomicAdd(&flags[1], sv);
}

// ---------------- ego -> bf16 X0 ----------------
__global__ __launch_bounds__(256)
void convert_kernel(const void* __restrict__ ue, const void* __restrict__ ie,
                    const int* __restrict__ flags, u16* __restrict__ x0,
                    int total, int usz) {
    int i = (blockIdx.x * blockDim.x + threadIdx.x) * 4;
    if (i >= total) return;
    const void* src = (i < usz) ? ue : ie;
    int off = (i < usz) ? i : i - usz;
    U4 o;
    if (flags[0] >= 512) {
        o = *(const U4*)((const u16*)src + off);
    } else {
        const float4 v = *(const float4*)((const float*)src + off);
        o.a = f2bf(v.x); o.b = f2bf(v.y); o.c = f2bf(v.z); o.d = f2bf(v.w);
    }
    *(U4*)(x0 + i) = o;
}

// ---------------- CSR row pointers ----------------
__global__ void hist_kernel(const int* __restrict__ row, int* __restrict__ cnt, int nnz) {
    int i = blockIdx.x * blockDim.x + threadIdx.x;
    if (i < nnz) atomicAdd(&cnt[row[i]], 1);
}

#define CHUNK 1024

__global__ __launch_bounds__(256)
void scan_partial_kernel(const int* __restrict__ cnt, int* __restrict__ part, int n) {
    __shared__ int sums[256];
    int b = blockIdx.x, t = threadIdx.x;
    int base = b * CHUNK + t * 4;
    int s = 0;
    for (int k = 0; k < 4; ++k) { int i = base + k; if (i < n) s += cnt[i]; }
    sums[t] = s;
    __syncthreads();
    for (int off = 1; off < 256; off <<= 1) {
        int y = (t >= off) ? sums[t - off] : 0;
        __syncthreads();
        sums[t] += y;
        __syncthreads();
    }
    if (t == 255) part[b] = sums[255];
}

__global__ void scan_part_kernel(int* __restrict__ part, int* __restrict__ rp,
                                 int nparts, int n) {
    __shared__ int buf[1024];
    int t = threadIdx.x;
    int v = (t < nparts) ? part[t] : 0;
    buf[t] = v;
    __syncthreads();
    for (int off = 1; off < 1024; off <<= 1) {
        int y = (t >= off) ? buf[t - off] : 0;
        __syncthreads();
        buf[t] += y;
        __syncthreads();
    }
    if (t < nparts) part[t] = buf[t] - v;
    if (t == 1023) rp[n] = buf[1023];
}

__global__ __launch_bounds__(256)
void scan_final_kernel(const int* __restrict__ cnt, const int* __restrict__ part,
                       int* __restrict__ rp, int* __restrict__ cursor, int n) {
    __shared__ int sums[256];
    int b = blockIdx.x, t = threadIdx.x;
    int base = b * CHUNK + t * 4;
    int v[4]; int s = 0;
    for (int k = 0; k < 4; ++k) { int i = base + k; v[k] = (i < n) ? cnt[i] : 0; s += v[k]; }
    sums[t] = s;
    __syncthreads();
    for (int off = 1; off < 256; off <<= 1) {
        int y = (t >= off) ? sums[t - off] : 0;
        __syncthreads();
        sums[t] += y;
        __syncthreads();
    }
    int running = part[b] + sums[t] - s;
    for (int k = 0; k < 4; ++k) {
        int i = base + k;
        if (i < n) { rp[i] = running; cursor[i] = running; }
        running += v[k];
    }
}

// bcursor[b] = start of bucket b's region in es2
__global__ void binit_kernel(const int* __restrict__ rp, int* __restrict__ bcursor, int n) {
    int b = threadIdx.x;  // 1 block, 512 threads
    int r = b * 512; if (r > n) r = n;
    bcursor[b] = rp[r];
}

// ---------------- coarse sort: COO -> bucket-grouped es2 ----------------
// es2 entry: .x = (row&511)<<18 | col   .y = val bits
__global__ __launch_bounds__(256)
void coarse_kernel(const int* __restrict__ row, const int* __restrict__ col,
                   const void* __restrict__ vals, const int* __restrict__ flags,
                   int* __restrict__ bcursor, int2* __restrict__ es2, int nnz) {
    __shared__ int2 ebuf[TILE];
    __shared__ u16  slotb[TILE];
    __shared__ int  hcnt[NBP], hscn[NBP], goff[NBP];
    int t = threadIdx.x;
    int base = blockIdx.x * TILE;
    int tcnt = nnz - base; if (tcnt > TILE) tcnt = TILE;
    bool vbf = (flags[1] >= 512);

    hcnt[t] = 0; hcnt[t + 256] = 0;
    __syncthreads();

    int eb[8], er[8], ep[8], ev[8];
#pragma unroll
    for (int k = 0; k < 8; ++k) {
        int i = base + k * 256 + t;
        eb[k] = -1;
        if (k * 256 + t < tcnt) {
            int r = row[i];
            int c = col[i];
            float v = vbf ? bf2f(((const u16*)vals)[i]) : ((const float*)vals)[i];
            eb[k] = r >> 9;
            ep[k] = ((r & 511) << 18) | c;
            ev[k] = __float_as_int(v);
            er[k] = atomicAdd(&hcnt[eb[k]], 1);
        }
    }
    __syncthreads();
    // exclusive scan of hcnt into hscn (inclusive then subtract)
    hscn[t] = hcnt[t]; hscn[t + 256] = hcnt[t + 256];
    __syncthreads();
    for (int off = 1; off < NBP; off <<= 1) {
        int a0 = (t >= off) ? hscn[t - off] : 0;
        int a1 = (t + 256 >= off) ? hscn[t + 256 - off] : 0;
        __syncthreads();
        hscn[t] += a0; hscn[t + 256] += a1;
        __syncthreads();
    }
#pragma unroll
    for (int k = 0; k < 8; ++k) {
        if (eb[k] >= 0) {
            int slot = hscn[eb[k]] - hcnt[eb[k]] + er[k];
            ebuf[slot] = make_int2(ep[k], ev[k]);
            slotb[slot] = (u16)eb[k];
        }
    }
    __syncthreads();
    // reserve global runs
    if (hcnt[t] > 0)       goff[t]       = atomicAdd(&bcursor[t],       hcnt[t]);
    if (hcnt[t + 256] > 0) goff[t + 256] = atomicAdd(&bcursor[t + 256], hcnt[t + 256]);
    __syncthreads();
    // copy out (runs are destination-contiguous)
#pragma unroll
    for (int k = 0; k < 8; ++k) {
        int p = k * 256 + t;
        if (p < tcnt) {
            int b = slotb[p];
            int dest = goff[b] + (p - (hscn[b] - hcnt[b]));
            es2[dest] = ebuf[p];
        }
    }
}

// ---------------- fine sort: bucket-quarter counting sort ----------------
__global__ __launch_bounds__(256)
void fine_kernel(const int2* __restrict__ es2, const int* __restrict__ rp,
                 int* __restrict__ cursor, int2* __restrict__ es, int n) {
    __shared__ int2 obuf[FCAP];
    __shared__ int hist[128], scn[128], cur[128];
    int b = blockIdx.x >> 2, q = blockIdx.x & 3, t = threadIdx.x;
    int r0 = b * 512; if (r0 > n) return;
    int r1 = r0 + 512; if (r1 > n) r1 = n;
    int qs = r0 + q * 128; if (qs >= r1) return;
    int qe = qs + 128; if (qe > r1) qe = r1;
    int s  = rp[r0], e = rp[r1];
    int ds = rp[qs];
    int qcnt = rp[qe] - ds;

    if (t < 128) hist[t] = 0;
    __syncthreads();

    if (qcnt <= FCAP) {
        // pass 1: count
        for (int i = s + t; i < e; i += 256) {
            int pk = es2[i].x;
            int rl = (unsigned)pk >> 18;
            if ((rl >> 7) == q) atomicAdd(&hist[rl & 127], 1);
        }
        __syncthreads();
        if (t < 128) scn[t] = hist[t];
        __syncthreads();
        for (int off = 1; off < 128; off <<= 1) {
            int a = (t >= off && t < 128) ? scn[t - off] : 0;
            __syncthreads();
            if (t < 128) scn[t] += a;
            __syncthreads();
        }
        if (t < 128) cur[t] = scn[t] - hist[t];   // exclusive
        __syncthreads();
        // pass 2: place into LDS
        for (int i = s + t; i < e; i += 256) {
            int2 p = es2[i];
            int rl = (unsigned)p.x >> 18;
            if ((rl >> 7) == q) {
                int pos = atomicAdd(&cur[rl & 127], 1);
                obuf[pos] = make_int2(p.x & 0x3FFFF, p.y);
            }
        }
        __syncthreads();
        // coalesced write of the sorted quarter
        for (int p = t; p < qcnt; p += 256)
            es[ds + p] = obuf[p];
    } else {
        // overflow fallback (statistically never): global-atomic scatter
        for (int i = s + t; i < e; i += 256) {
            int2 p = es2[i];
            int rl = (unsigned)p.x >> 18;
            if ((rl >> 7) == q) {
                int pos = atomicAdd(&cursor[r0 + rl], 1);
                es[pos] = make_int2(p.x & 0x3FFFF, p.y);
            }
        }
    }
}

// ---------------- SpMM (one wave/row, lane = dim, x8 edge unroll) ----------------

__global__ __launch_bounds__(256)
void spmm_kernel(const u16* __restrict__ x, u16* __restrict__ y,
                 const int* __restrict__ rp, const int2* __restrict__ es, int n) {
    int wid  = (blockIdx.x * blockDim.x + threadIdx.x) >> 6;
    int lane = threadIdx.x & 63;
    if (wid >= n) return;
    int e0 = rp[wid], e1 = rp[wid + 1];
    float a0 = 0.f, a1 = 0.f, a2 = 0.f, a3 = 0.f;
    float a4 = 0.f, a5 = 0.f, a6 = 0.f, a7 = 0.f;
    int e = e0;
    for (; e + 8 <= e1; e += 8) {
        int2 p0 = es[e],     p1 = es[e + 1], p2 = es[e + 2], p3 = es[e + 3];
        int2 p4 = es[e + 4], p5 = es[e + 5], p6 = es[e + 6], p7 = es[e + 7];
        a0 += __int_as_float(p0.y) * bf2f(x[(p0.x << 6) + lane]);
        a1 += __int_as_float(p1.y) * bf2f(x[(p1.x << 6) + lane]);
        a2 += __int_as_float(p2.y) * bf2f(x[(p2.x << 6) + lane]);
        a3 += __int_as_float(p3.y) * bf2f(x[(p3.x << 6) + lane]);
        a4 += __int_as_float(p4.y) * bf2f(x[(p4.x << 6) + lane]);
        a5 += __int_as_float(p5.y) * bf2f(x[(p5.x << 6) + lane]);
        a6 += __int_as_float(p6.y) * bf2f(x[(p6.x << 6) + lane]);
        a7 += __int_as_float(p7.y) * bf2f(x[(p7.x << 6) + lane]);
    }
    for (; e < e1; ++e) {
        int2 p = es[e];
        a0 += __int_as_float(p.y) * bf2f(x[(p.x << 6) + lane]);
    }
    float acc = ((a0 + a1) + (a2 + a3)) + ((a4 + a5) + (a6 + a7));
    y[(wid << 6) + lane] = f2bf(acc);
}

__global__ __launch_bounds__(256)
void spmm_last_kernel(const u16* __restrict__ x2, const u16* __restrict__ x1,
                      float* __restrict__ out,
                      const int* __restrict__ rp, const int2* __restrict__ es, int n) {
    int wid  = (blockIdx.x * blockDim.x + threadIdx.x) >> 6;
    int lane = threadIdx.x & 63;
    if (wid >= n) return;
    int e0 = rp[wid], e1 = rp[wid + 1];
    float a0 = 0.f, a1 = 0.f, a2 = 0.f, a3 = 0.f;
    float a4 = 0.f, a5 = 0.f, a6 = 0.f, a7 = 0.f;
    int e = e0;
    for (; e + 8 <= e1; e += 8) {
        int2 p0 = es[e],     p1 = es[e + 1], p2 = es[e + 2], p3 = es[e + 3];
        int2 p4 = es[e + 4], p5 = es[e + 5], p6 = es[e + 6], p7 = es[e + 7];
        a0 += __int_as_float(p0.y) * bf2f(x2[(p0.x << 6) + lane]);
        a1 += __int_as_float(p1.y) * bf2f(x2[(p1.x << 6) + lane]);
        a2 += __int_as_float(p2.y) * bf2f(x2[(p2.x << 6) + lane]);
        a3 += __int_as_float(p3.y) * bf2f(x2[(p3.x << 6) + lane]);
        a4 += __int_as_float(p4.y) * bf2f(x2[(p4.x << 6) + lane]);
        a5 += __int_as_float(p5.y) * bf2f(x2[(p5.x << 6) + lane]);
        a6 += __int_as_float(p6.y) * bf2f(x2[(p6.x << 6) + lane]);
        a7 += __int_as_float(p7.y) * bf2f(x2[(p7.x << 6) + lane]);
    }
    for (; e < e1; ++e) {
        int2 p = es[e];
        a0 += __int_as_float(p.y) * bf2f(x2[(p.x << 6) + lane]);
    }
    float acc = ((a0 + a1) + (a2 + a3)) + ((a4 + a5) + (a6 + a7));
    int idx = (wid << 6) + lane;
    float h1 = bf2f(x1[idx]);
    float h2 = bf2f(x2[idx]);
    out[idx] = (h1 + h2 + acc) * (1.0f / 3.0f);
    out[(size_t)n * D + idx] = h1;
}

// ---------------- launch ----------------

extern "C" void kernel_launch(void* const* d_in, const int* in_sizes, int n_in,
                              void* d_out, int out_size, void* d_ws, size_t ws_size,
                              hipStream_t stream) {
    const void* ue   = d_in[0];
    const void* ie   = d_in[1];
    const int*  row  = (const int*)d_in[2];
    const int*  col  = (const int*)d_in[3];
    const void* vals = d_in[4];

    const int nu  = in_sizes[0] / D;   // 100000
    const int ni  = in_sizes[1] / D;   //  50000
    const int n   = nu + ni;           // 150000
    const int nnz = in_sizes[2];       // 4800000

    // workspace (~98.5 MB). es2 aliases X1+X2 (dead before spmm writes X1).
    char* ws = (char*)d_ws;
    u16*  X0     = (u16*)ws;   ws += (size_t)n * D * sizeof(u16);
    u16*  X1     = (u16*)ws;   ws += (size_t)n * D * sizeof(u16);
    u16*  X2     = (u16*)ws;   ws += (size_t)n * D * sizeof(u16);
    int2* es2    = (int2*)X1;  // nnz*8B == 2*n*D*2B exactly
    int2* es     = (int2*)ws;  ws += (size_t)nnz * sizeof(int2);
    int*  rp     = (int*)ws;   ws += (size_t)(n + 1) * sizeof(int);
    int*  cnt    = (int*)ws;   ws += (size_t)n * sizeof(int);
    int*  cursor = (int*)ws;   ws += (size_t)n * sizeof(int);
    int*  part   = (int*)ws;   ws += 1024 * sizeof(int);
    int*  bcursor= (int*)ws;   ws += NBP * sizeof(int);
    int*  flags  = (int*)ws;   ws += 2 * sizeof(int);

    const int tb = 256;
    const int eblocks = (nnz + tb - 1) / tb;
    const int rblocks = (n + 3) / 4;
    const int cblocks = (n * D / 4 + tb - 1) / tb;
    const int sblocks = (n + CHUNK - 1) / CHUNK;
    const int NB      = (n + 511) / 512;            // 293
    const int coarseb = (nnz + TILE - 1) / TILE;    // 2344

    hipMemsetAsync(cnt, 0, ((size_t)2 * n + 1024 + NBP + 2) * sizeof(int), stream);
    detect_kernel      <<<1, 64, 0, stream>>>((const u16*)ue, (const u16*)vals, flags);
    convert_kernel     <<<cblocks, tb, 0, stream>>>(ue, ie, flags, X0, n * D, nu * D);
    hist_kernel        <<<eblocks, tb, 0, stream>>>(row, cnt, nnz);
    scan_partial_kernel<<<sblocks, tb, 0, stream>>>(cnt, part, n);
    scan_part_kernel   <<<1, 1024, 0, stream>>>(part, rp, sblocks, n);
    scan_final_kernel  <<<sblocks, tb, 0, stream>>>(cnt, part, rp, cursor, n);
    binit_kernel       <<<1, NBP, 0, stream>>>(rp, bcursor, n);
    coarse_kernel      <<<coarseb, tb, 0, stream>>>(row, col, vals, flags, bcursor, es2, nnz);
    fine_kernel        <<<NB * 4, tb, 0, stream>>>(es2, rp, cursor, es, n);

    spmm_kernel     <<<rblocks, tb, 0, stream>>>(X0, X1, rp, es, n);
    spmm_kernel     <<<rblocks, tb, 0, stream>>>(X1, X2, rp, es, n);
    spmm_last_kernel<<<rblocks, tb, 0, stream>>>(X2, X1, (float*)d_out, rp, es, n);
}

// Round 6
// 792.727 us; speedup vs baseline: 2.7391x; 1.2009x over previous
//
#include <hip/hip_runtime.h>
#include <hip/hip_bf16.h>

// LightGCN 3-hop GraphConv (M4_86749749444857).
// R5->R6: row-granular hist_kernel (187us, 150MB atomic write traffic) and the
// n-wide 3-kernel scan are gone. Bucket-level LDS histogram (293 counters) +
// 1-block bucket scan give exact es2 bucket bases; fine_kernel now computes
// hist[512] per bucket in LDS and emits row-level rp itself.

#define D 64
typedef unsigned short u16;

#define NBP   512    // padded bucket count (real NB = ceil(n/512) = 293)
#define TILE  2048   // edges per coarse block
#define FCAP  4608   // fine LDS slots (lambda=4096 + 8 sigma)

__device__ __forceinline__ float bf2f(u16 h) {
    union { unsigned int u; float f; } c;
    c.u = ((unsigned int)h) << 16;
    return c.f;
}
__device__ __forceinline__ u16 f2bf(float f) {
    union { float f; unsigned int u; } c; c.f = f;
    unsigned int r = c.u + 0x7FFFu + ((c.u >> 16) & 1u);  // RNE
    return (u16)(r >> 16);
}

struct U4 { u16 a, b, c, d; } __attribute__((aligned(8)));

// ---------------- dtype sniffing ----------------
__global__ void detect_kernel(const u16* __restrict__ emb,
                              const u16* __restrict__ vals,
                              int* __restrict__ flags) {
    int lane = threadIdx.x;  // 64 threads, 1 block
    int se = 0, sv = 0;
    for (int k = 0; k < 16; ++k) {
        int idx = (lane * 16 + k) * 2;
        u16 he = emb[idx];
        int ee = (he >> 7) & 0xFF;
        if (ee >= 100 && ee < 127) se++;
        u16 hv = vals[idx];
        int ev = (hv >> 7) & 0xFF;
        if ((hv >> 15) == 0 && ev >= 60 && ev < 123) sv++;
    }
    atomicAdd(&flags[0], se);
    atomicAdd(&flags[1], sv);
}

// ---------------- ego -> bf16 X0 ----------------
__global__ __launch_bounds__(256)
void convert_kernel(const void* __restrict__ ue, const void* __restrict__ ie,
                    const int* __restrict__ flags, u16* __restrict__ x0,
                    int total, int usz) {
    int i = (blockIdx.x * blockDim.x + threadIdx.x) * 4;
    if (i >= total) return;
    const void* src = (i < usz) ? ue : ie;
    int off = (i < usz) ? i : i - usz;
    U4 o;
    if (flags[0] >= 512) {
        o = *(const U4*)((const u16*)src + off);
    } else {
        const float4 v = *(const float4*)((const float*)src + off);
        o.a = f2bf(v.x); o.b = f2bf(v.y); o.c = f2bf(v.z); o.d = f2bf(v.w);
    }
    *(U4*)(x0 + i) = o;
}

// ---------------- bucket histogram (LDS-aggregated) ----------------
__global__ __launch_bounds__(256)
void bhist_kernel(const int* __restrict__ row, int* __restrict__ bcnt, int nnz) {
    __shared__ int h[NBP];
    int t = threadIdx.x;
    h[t] = 0; h[t + 256] = 0;
    __syncthreads();
    for (int i = blockIdx.x * 256 + t; i < nnz; i += gridDim.x * 256)
        atomicAdd(&h[row[i] >> 9], 1);
    __syncthreads();
    if (h[t])       atomicAdd(&bcnt[t],       h[t]);
    if (h[t + 256]) atomicAdd(&bcnt[t + 256], h[t + 256]);
}

// single block, 512 threads: exclusive scan of bucket counts
__global__ void bscan_kernel(const int* __restrict__ bcnt, int* __restrict__ bbase,
                             int* __restrict__ bcursor, int nb, int nnz) {
    __shared__ int buf[NBP];
    int t = threadIdx.x;
    int v = (t < nb) ? bcnt[t] : 0;
    buf[t] = v;
    __syncthreads();
    for (int off = 1; off < NBP; off <<= 1) {
        int y = (t >= off) ? buf[t - off] : 0;
        __syncthreads();
        buf[t] += y;
        __syncthreads();
    }
    int excl = buf[t] - v;
    bbase[t] = excl;
    bcursor[t] = excl;
    if (t == 0) bbase[nb] = nnz;
}

// ---------------- coarse sort: COO -> bucket-grouped es2 ----------------
// es2 entry: .x = (row&511)<<18 | col   .y = val bits
__global__ __launch_bounds__(256)
void coarse_kernel(const int* __restrict__ row, const int* __restrict__ col,
                   const void* __restrict__ vals, const int* __restrict__ flags,
                   int* __restrict__ bcursor, int2* __restrict__ es2, int nnz) {
    __shared__ int2 ebuf[TILE];
    __shared__ u16  slotb[TILE];
    __shared__ int  hcnt[NBP], hscn[NBP], goff[NBP];
    int t = threadIdx.x;
    int base = blockIdx.x * TILE;
    int tcnt = nnz - base; if (tcnt > TILE) tcnt = TILE;
    bool vbf = (flags[1] >= 512);

    hcnt[t] = 0; hcnt[t + 256] = 0;
    __syncthreads();

    int eb[8], er[8], ep[8], ev[8];
#pragma unroll
    for (int k = 0; k < 8; ++k) {
        int i = base + k * 256 + t;
        eb[k] = -1;
        if (k * 256 + t < tcnt) {
            int r = row[i];
            int c = col[i];
            float v = vbf ? bf2f(((const u16*)vals)[i]) : ((const float*)vals)[i];
            eb[k] = r >> 9;
            ep[k] = ((r & 511) << 18) | c;
            ev[k] = __float_as_int(v);
            er[k] = atomicAdd(&hcnt[eb[k]], 1);
        }
    }
    __syncthreads();
    hscn[t] = hcnt[t]; hscn[t + 256] = hcnt[t + 256];
    __syncthreads();
    for (int off = 1; off < NBP; off <<= 1) {
        int a0 = (t >= off) ? hscn[t - off] : 0;
        int a1 = (t + 256 >= off) ? hscn[t + 256 - off] : 0;
        __syncthreads();
        hscn[t] += a0; hscn[t + 256] += a1;
        __syncthreads();
    }
#pragma unroll
    for (int k = 0; k < 8; ++k) {
        if (eb[k] >= 0) {
            int slot = hscn[eb[k]] - hcnt[eb[k]] + er[k];
            ebuf[slot] = make_int2(ep[k], ev[k]);
            slotb[slot] = (u16)eb[k];
        }
    }
    __syncthreads();
    if (hcnt[t] > 0)       goff[t]       = atomicAdd(&bcursor[t],       hcnt[t]);
    if (hcnt[t + 256] > 0) goff[t + 256] = atomicAdd(&bcursor[t + 256], hcnt[t + 256]);
    __syncthreads();
#pragma unroll
    for (int k = 0; k < 8; ++k) {
        int p = k * 256 + t;
        if (p < tcnt) {
            int b = slotb[p];
            int dest = goff[b] + (p - (hscn[b] - hcnt[b]));
            es2[dest] = ebuf[p];
        }
    }
}

// ---------------- fine sort + rp emit: bucket-quarter counting sort ----------
__global__ __launch_bounds__(256)
void fine_kernel(const int2* __restrict__ es2, const int* __restrict__ bbase,
                 int2* __restrict__ es, int* __restrict__ rp, int n, int nnz) {
    __shared__ int2 obuf[FCAP];
    __shared__ int hist[512], scn[512], cur[128];
    int b = blockIdx.x >> 2, q = blockIdx.x & 3, t = threadIdx.x;
    int r0 = b * 512;
    int s = bbase[b], e = bbase[b + 1];
    if (b == 0 && q == 0 && t == 0) rp[n] = nnz;

    hist[t] = 0; hist[t + 256] = 0;
    __syncthreads();
    for (int i = s + t; i < e; i += 256)
        atomicAdd(&hist[(unsigned)es2[i].x >> 18], 1);
    __syncthreads();
    scn[t] = hist[t]; scn[t + 256] = hist[t + 256];
    __syncthreads();
    for (int off = 1; off < 512; off <<= 1) {
        int a0 = (t >= off) ? scn[t - off] : 0;
        int a1 = (t + 256 >= off) ? scn[t + 256 - off] : 0;
        __syncthreads();
        scn[t] += a0; scn[t + 256] += a1;
        __syncthreads();
    }
    // scn = inclusive prefix of hist; excl[rl] = scn[rl] - hist[rl]
    int qbase = q * 128;
    int q0 = qbase ? scn[qbase - 1] : 0;                 // excl prefix at quarter start
    int qcnt = scn[qbase + 127] - q0;
    int ds = s + q0;

    if (t < 128) {
        int rl = qbase + t;
        int r  = r0 + rl;
        int ex = scn[rl] - hist[rl];
        if (r < n) rp[r] = s + ex;
        cur[t] = (qcnt <= FCAP) ? (ex - q0) : (s + ex);  // LDS slot vs global dest
    }
    __syncthreads();

    if (qcnt <= FCAP) {
        for (int i = s + t; i < e; i += 256) {
            int2 p = es2[i];
            int rl = (unsigned)p.x >> 18;
            if ((rl >> 7) == q) {
                int pos = atomicAdd(&cur[rl & 127], 1);
                obuf[pos] = make_int2(p.x & 0x3FFFF, p.y);
            }
        }
        __syncthreads();
        for (int p = t; p < qcnt; p += 256)
            es[ds + p] = obuf[p];
    } else {
        // statistically-unreachable overflow: direct global scatter via LDS cursors
        for (int i = s + t; i < e; i += 256) {
            int2 p = es2[i];
            int rl = (unsigned)p.x >> 18;
            if ((rl >> 7) == q) {
                int pos = atomicAdd(&cur[rl & 127], 1);
                es[pos] = make_int2(p.x & 0x3FFFF, p.y);
            }
        }
    }
}

// ---------------- SpMM (one wave/row, lane = dim, x8 edge unroll) ----------------

__global__ __launch_bounds__(256)
void spmm_kernel(const u16* __restrict__ x, u16* __restrict__ y,
                 const int* __restrict__ rp, const int2* __restrict__ es, int n) {
    int wid  = (blockIdx.x * blockDim.x + threadIdx.x) >> 6;
    int lane = threadIdx.x & 63;
    if (wid >= n) return;
    int e0 = rp[wid], e1 = rp[wid + 1];
    float a0 = 0.f, a1 = 0.f, a2 = 0.f, a3 = 0.f;
    float a4 = 0.f, a5 = 0.f, a6 = 0.f, a7 = 0.f;
    int e = e0;
    for (; e + 8 <= e1; e += 8) {
        int2 p0 = es[e],     p1 = es[e + 1], p2 = es[e + 2], p3 = es[e + 3];
        int2 p4 = es[e + 4], p5 = es[e + 5], p6 = es[e + 6], p7 = es[e + 7];
        a0 += __int_as_float(p0.y) * bf2f(x[(p0.x << 6) + lane]);
        a1 += __int_as_float(p1.y) * bf2f(x[(p1.x << 6) + lane]);
        a2 += __int_as_float(p2.y) * bf2f(x[(p2.x << 6) + lane]);
        a3 += __int_as_float(p3.y) * bf2f(x[(p3.x << 6) + lane]);
        a4 += __int_as_float(p4.y) * bf2f(x[(p4.x << 6) + lane]);
        a5 += __int_as_float(p5.y) * bf2f(x[(p5.x << 6) + lane]);
        a6 += __int_as_float(p6.y) * bf2f(x[(p6.x << 6) + lane]);
        a7 += __int_as_float(p7.y) * bf2f(x[(p7.x << 6) + lane]);
    }
    for (; e < e1; ++e) {
        int2 p = es[e];
        a0 += __int_as_float(p.y) * bf2f(x[(p.x << 6) + lane]);
    }
    float acc = ((a0 + a1) + (a2 + a3)) + ((a4 + a5) + (a6 + a7));
    y[(wid << 6) + lane] = f2bf(acc);
}

__global__ __launch_bounds__(256)
void spmm_last_kernel(const u16* __restrict__ x2, const u16* __restrict__ x1,
                      float* __restrict__ out,
                      const int* __restrict__ rp, const int2* __restrict__ es, int n) {
    int wid  = (blockIdx.x * blockDim.x + threadIdx.x) >> 6;
    int lane = threadIdx.x & 63;
    if (wid >= n) return;
    int e0 = rp[wid], e1 = rp[wid + 1];
    float a0 = 0.f, a1 = 0.f, a2 = 0.f, a3 = 0.f;
    float a4 = 0.f, a5 = 0.f, a6 = 0.f, a7 = 0.f;
    int e = e0;
    for (; e + 8 <= e1; e += 8) {
        int2 p0 = es[e],     p1 = es[e + 1], p2 = es[e + 2], p3 = es[e + 3];
        int2 p4 = es[e + 4], p5 = es[e + 5], p6 = es[e + 6], p7 = es[e + 7];
        a0 += __int_as_float(p0.y) * bf2f(x2[(p0.x << 6) + lane]);
        a1 += __int_as_float(p1.y) * bf2f(x2[(p1.x << 6) + lane]);
        a2 += __int_as_float(p2.y) * bf2f(x2[(p2.x << 6) + lane]);
        a3 += __int_as_float(p3.y) * bf2f(x2[(p3.x << 6) + lane]);
        a4 += __int_as_float(p4.y) * bf2f(x2[(p4.x << 6) + lane]);
        a5 += __int_as_float(p5.y) * bf2f(x2[(p5.x << 6) + lane]);
        a6 += __int_as_float(p6.y) * bf2f(x2[(p6.x << 6) + lane]);
        a7 += __int_as_float(p7.y) * bf2f(x2[(p7.x << 6) + lane]);
    }
    for (; e < e1; ++e) {
        int2 p = es[e];
        a0 += __int_as_float(p.y) * bf2f(x2[(p.x << 6) + lane]);
    }
    float acc = ((a0 + a1) + (a2 + a3)) + ((a4 + a5) + (a6 + a7));
    int idx = (wid << 6) + lane;
    float h1 = bf2f(x1[idx]);
    float h2 = bf2f(x2[idx]);
    out[idx] = (h1 + h2 + acc) * (1.0f / 3.0f);
    out[(size_t)n * D + idx] = h1;
}

// ---------------- launch ----------------

extern "C" void kernel_launch(void* const* d_in, const int* in_sizes, int n_in,
                              void* d_out, int out_size, void* d_ws, size_t ws_size,
                              hipStream_t stream) {
    const void* ue   = d_in[0];
    const void* ie   = d_in[1];
    const int*  row  = (const int*)d_in[2];
    const int*  col  = (const int*)d_in[3];
    const void* vals = d_in[4];

    const int nu  = in_sizes[0] / D;   // 100000
    const int ni  = in_sizes[1] / D;   //  50000
    const int n   = nu + ni;           // 150000
    const int nnz = in_sizes[2];       // 4800000

    // workspace (~97 MB). es2 aliases X1+X2 (dead before spmm writes X1).
    char* ws = (char*)d_ws;
    u16*  X0     = (u16*)ws;   ws += (size_t)n * D * sizeof(u16);
    u16*  X1     = (u16*)ws;   ws += (size_t)n * D * sizeof(u16);
    u16*  X2     = (u16*)ws;   ws += (size_t)n * D * sizeof(u16);
    int2* es2    = (int2*)X1;  // nnz*8B == 2*n*D*2B exactly
    int2* es     = (int2*)ws;  ws += (size_t)nnz * sizeof(int2);
    int*  rp     = (int*)ws;   ws += (size_t)(n + 1) * sizeof(int);
    int*  bcnt   = (int*)ws;   ws += NBP * sizeof(int);
    int*  flags  = (int*)ws;   ws += 2 * sizeof(int);
    int*  bbase  = (int*)ws;   ws += (NBP + 1) * sizeof(int);
    int*  bcursor= (int*)ws;   ws += NBP * sizeof(int);

    const int tb = 256;
    const int rblocks = (n + 3) / 4;
    const int cblocks = (n * D / 4 + tb - 1) / tb;
    const int NB      = (n + 511) / 512;            // 293
    const int coarseb = (nnz + TILE - 1) / TILE;    // 2344

    // zero bcnt + flags (contiguous)
    hipMemsetAsync(bcnt, 0, (NBP + 2) * sizeof(int), stream);
    detect_kernel <<<1, 64, 0, stream>>>((const u16*)ue, (const u16*)vals, flags);
    convert_kernel<<<cblocks, tb, 0, stream>>>(ue, ie, flags, X0, n * D, nu * D);
    bhist_kernel  <<<512, tb, 0, stream>>>(row, bcnt, nnz);
    bscan_kernel  <<<1, NBP, 0, stream>>>(bcnt, bbase, bcursor, NB, nnz);
    coarse_kernel <<<coarseb, tb, 0, stream>>>(row, col, vals, flags, bcursor, es2, nnz);
    fine_kernel   <<<NB * 4, tb, 0, stream>>>(es2, bbase, es, rp, n, nnz);

    spmm_kernel     <<<rblocks, tb, 0, stream>>>(X0, X1, rp, es, n);
    spmm_kernel     <<<rblocks, tb, 0, stream>>>(X1, X2, rp, es, n);
    spmm_last_kernel<<<rblocks, tb, 0, stream>>>(X2, X1, (float*)d_out, rp, es, n);
}